// Round 4
// baseline (31487.888 us; speedup 1.0000x reference)
//
#include <hip/hip_runtime.h>

// ---------------------------------------------------------------------------
// NS_Flashed_TotalSimRetina — GLM retina simulation, round 9.
// Rounds 6-8 all compiled to VGPR_Count=84 regardless of budget attrs
// (default / launch_bounds(600,1) / waves_per_eu(3,3)) -> the spill is a
// LIVE-RANGE problem, not a budget problem: the cell-transposed weight
// layout W[k][c] has k-stride 9600B > 4095 (global-load imm range), so all
// 25 unrolled loads per block need their own 64-bit address regs (~+50
// live) on top of acc[100] -> live set > the 168 hard cap for a 600-thread
// wg -> allocator collapse (84 + full scratch residency; 1 GB scratch
// writes, 67 us/step latency-serialized).
// Fix: 4-cell-interleaved weight layout W[c/4][k][c%4] (uint4 granular):
//   - ONE base pointer per lane, all 275 tap-block loads at compile-time
//     offsets k*64B (compiler anchors a few bases + folds immediates);
//     round 5 proved this codegen shape fits (136 VGPRs).
//   - lane quads read contiguous 64B lines -> 16 segments/instr (4x lighter
//     on the TA than fully per-cell; same L2 bytes, table stays L2-resident).
// Everything else unchanged from round 8 (per-batch wg, LDS spike exchange,
// unroll-1 p-loop, per-pair LDS gather).
// ---------------------------------------------------------------------------

#define NC     600
#define NPIX   4096
#define NBF    100
#define MC     20
#define NB     500
#define NBI    100
#define NBATCH 32
#define NSTEP  400

typedef unsigned int u32;
typedef _Float16 f16x2 __attribute__((ext_vector_type(2)));

__device__ __forceinline__ float dot2(u32 a, u32 b, float acc) {
  return __builtin_amdgcn_fdot2(__builtin_bit_cast(f16x2, a),
                                __builtin_bit_cast(f16x2, b), acc, false);
}
__device__ __forceinline__ u32 pkrtz(float a, float b) {
  return __builtin_bit_cast(u32, __builtin_amdgcn_cvt_pkrtz(a, b));
}

// --- stim_applied[b][c] = sum_p stim[b][p] * spat[c][p] ---------------------
__global__ void applied_kernel(const float* __restrict__ stim,
                               const float* __restrict__ spat,
                               float* __restrict__ applied) {
  const int c = blockIdx.x, b = blockIdx.y;
  __shared__ float red[256];
  float a = 0.f;
  for (int p = threadIdx.x; p < NPIX; p += 256)
    a += stim[b * NPIX + p] * spat[c * NPIX + p];
  red[threadIdx.x] = a;
  __syncthreads();
  for (int s = 128; s > 0; s >>= 1) {
    if (threadIdx.x < s) red[threadIdx.x] += red[threadIdx.x + s];
    __syncthreads();
  }
  if (threadIdx.x == 0) applied[b * NC + c] = red[0];
}

// --- convT[t][c] = sum_f stc[t+f] * tcf[c][f] ------------------------------
__global__ void conv_kernel(const float* __restrict__ stc,
                            const float* __restrict__ tcf,
                            float* __restrict__ convT) {
  int idx = blockIdx.x * 256 + threadIdx.x;
  if (idx >= NSTEP * NC) return;
  int t = idx / NC, c = idx - t * NC;
  float a = 0.f;
  for (int f = 0; f < NBF; ++f)
    a += stc[t + f] * tcf[c * NBF + f];
  convT[idx] = a;
}

// --- packed, time-reversed, edge-paired, 4-CELL-INTERLEAVED filter table ---
// Logical per-cell stream: tap-block k = p*25 + (i>>2) for pair p<10,
// k = 250 + (i>>2) for feedback; element j = i&3 within the uint4.
// Stored at uint4 index ((c>>2)*275 + k)*4 + (c&3):
//   - lane c's 275 blocks are at ONE base + offsets k*64B (imm-foldable)
//   - lane quads (4 consecutive c) read contiguous 64B lines.
__global__ void pack_kernel(const float* __restrict__ cf,
                            const float* __restrict__ ff,
                            u32* __restrict__ wPT) {
  int idx = blockIdx.x * 256 + threadIdx.x;
  if (idx >= NC * 1100) return;
  int c = idx / 1100;
  int r = idx - c * 1100;
  int p = r / 100;
  int i = r - p * 100;
  int f = 99 - i;
  float lo, hi;
  if (p < 10) {
    lo = cf[(c * MC + 2 * p) * NBF + f];
    hi = cf[(c * MC + 2 * p + 1) * NBF + f];
  } else {
    lo = ff[c * NBF + f];
    hi = 0.f;
  }
  const int k = p * 25 + (i >> 2);
  wPT[((((c >> 2) * 275 + k) * 4 + (c & 3)) << 2) + (i & 3)] = pkrtz(lo, hi);
}

// --- packed source pairs, transposed: selpT[p][c] = src0 | (src1 << 16) ----
__global__ void selp_kernel(const int* __restrict__ sel, u32* __restrict__ selpT) {
  int idx = blockIdx.x * 256 + threadIdx.x;
  if (idx >= NC * 10) return;
  int c = idx / 10, p = idx - c * 10;
  u32 s0 = (u32)sel[c * MC + 2 * p];
  u32 s1 = (u32)sel[c * MC + 2 * p + 1];
  selpT[p * NC + c] = s0 | (s1 << 16);
}

// --- initT2[b][tau][c] = init[b][c][tau]  (coalesced per-step reads) -------
__global__ void initT2_kernel(const float* __restrict__ init,
                              float* __restrict__ initT2) {
  int idx = blockIdx.x * 256 + threadIdx.x;
  if (idx >= NBATCH * NBI * NC) return;
  int c = idx % NC;
  int r = idx / NC;
  int tau = r % NBI;
  int b = r / NBI;
  initT2[idx] = init[(b * NC + c) * NBI + tau];
}

// --- copy initial spikes into output (first 100 bins of each row) ----------
__global__ void copy_init_kernel(const float4* __restrict__ init,
                                 float4* __restrict__ out) {
  int idx = blockIdx.x * 256 + threadIdx.x;
  if (idx >= NBATCH * NC * (NBI / 4)) return;
  int k4 = idx % (NBI / 4);
  int bc = idx / (NBI / 4);
  out[bc * (NB / 4) + k4] = init[idx];
}

// --- the recurrence: one workgroup per batch, LDS spike exchange -----------
__global__ __attribute__((amdgpu_flat_work_group_size(600, 600)))
__attribute__((amdgpu_waves_per_eu(2, 3)))
void sim_kernel(
    const float* __restrict__ bias, const float* __restrict__ applied,
    const float* __restrict__ convT, const uint4* __restrict__ wp,
    const u32* __restrict__ selpT, const float* __restrict__ initT2,
    float* __restrict__ out) {
  const int c = threadIdx.x;     // cell, 0..599
  const int b = blockIdx.x;      // batch, 0..31

  __shared__ float spk[2][NC];   // double-buffered current-step spikes

  float acc[NBF];
#pragma unroll
  for (int i = 0; i < NBF; ++i) acc[i] = 0.f;

  u32 selpv[10];
#pragma unroll
  for (int p = 0; p < 10; ++p) selpv[p] = selpT[p * NC + c];  // coalesced

  const float biasv = bias[c];
  const float appv  = applied[b * NC + c];
  const float* ib2  = initT2 + (size_t)b * NBI * NC;
  float* outS = out + (size_t)(b * NC + c) * NB + NBI;
  float* outG = out + (size_t)NBATCH * NC * NB + (size_t)(b * NC + c) * NSTEP;

  // single per-lane weight base; tap-block k lives at wc[k*4] (offset k*64B)
  const uint4* wc = wp + ((c >> 2) * 1100 + (c & 3));

#pragma unroll 1
  for (int tau = 0; tau < NB; ++tau) {
    const int t  = tau - NBI;
    const int pb = tau & 1;
    float sv;
    if (t >= 0) {
      float g = biasv + appv * convT[t * NC + c] + acc[0];
      sv = 1.f / (1.f + __expf(-g));
      outS[t] = sv;
      outG[t] = g;
    } else {
      sv = ib2[tau * NC + c];
    }
    spk[pb][c] = sv;

    // rotate: acc[i] <- contributions to step (tau+1)+i
#pragma unroll
    for (int i = 0; i < NBF - 1; ++i) acc[i] = acc[i + 1];
    acc[NBF - 1] = 0.f;

    // feedback scatter (own spike, k = 250..274) — before the barrier
    {
      const u32 sp10 = pkrtz(sv, 0.f);
#pragma unroll
      for (int ib = 0; ib < 25; ++ib) {
        const uint4 w = wc[(250 + ib) * 4];
        acc[ib * 4 + 0] = dot2(w.x, sp10, acc[ib * 4 + 0]);
        acc[ib * 4 + 1] = dot2(w.y, sp10, acc[ib * 4 + 1]);
        acc[ib * 4 + 2] = dot2(w.z, sp10, acc[ib * 4 + 2]);
        acc[ib * 4 + 3] = dot2(w.w, sp10, acc[ib * 4 + 3]);
      }
    }

    __syncthreads();   // all 600 spikes of this batch now visible in LDS

    // coupling scatter: acc[i] += w[p][i] . sp   (1000 dot2)
#pragma unroll 1
    for (int p = 0; p < 10; ++p) {
      const u32 s01 = selpv[p];
      const u32 sp2 = pkrtz(spk[pb][s01 & 0xffffu], spk[pb][s01 >> 16]);
#pragma unroll
      for (int ib = 0; ib < 25; ++ib) {
        const uint4 w = wc[(p * 25 + ib) * 4];
        acc[ib * 4 + 0] = dot2(w.x, sp2, acc[ib * 4 + 0]);
        acc[ib * 4 + 1] = dot2(w.y, sp2, acc[ib * 4 + 1]);
        acc[ib * 4 + 2] = dot2(w.z, sp2, acc[ib * 4 + 2]);
        acc[ib * 4 + 3] = dot2(w.w, sp2, acc[ib * 4 + 3]);
      }
    }
    // no second barrier needed: next write touches spk[pb^1]; the next
    // iteration's __syncthreads orders it before any reuse of spk[pb].
  }
}

extern "C" void kernel_launch(void* const* d_in, const int* in_sizes, int n_in,
                              void* d_out, int out_size, void* d_ws, size_t ws_size,
                              hipStream_t stream) {
  const float* stim = (const float*)d_in[0];   // 32x64x64
  const float* init = (const float*)d_in[1];   // 32x600x100
  const float* spat = (const float*)d_in[2];   // 600x4096
  const float* tcf  = (const float*)d_in[3];   // 600x100
  const float* ff   = (const float*)d_in[4];   // 600x100
  const float* cf   = (const float*)d_in[5];   // 600x20x100
  const float* bias = (const float*)d_in[6];   // 600x1
  const int*   sel  = (const int*)d_in[7];     // 600x20 int32
  const float* stc  = (const float*)d_in[8];   // 500
  float* out = (float*)d_out;                  // spikes 32x600x500, gensig 32x600x400

  char* ws = (char*)d_ws;
  float* applied = (float*)ws;                       //     76,800 B
  float* convT   = (float*)(ws + 76800);             //    960,000 B
  u32*   wPT     = (u32*)(ws + 1036800);             //  2,640,000 B
  u32*   selpT   = (u32*)(ws + 3676800);             //     24,000 B
  float* initT2  = (float*)(ws + 3700800);           //  7,680,000 B (end ~11.4 MB)
  (void)ws_size; (void)in_sizes; (void)n_in; (void)out_size;

  hipLaunchKernelGGL(applied_kernel, dim3(NC, NBATCH), dim3(256), 0, stream,
                     stim, spat, applied);
  hipLaunchKernelGGL(conv_kernel, dim3((NSTEP * NC + 255) / 256), dim3(256), 0,
                     stream, stc, tcf, convT);
  hipLaunchKernelGGL(pack_kernel, dim3((NC * 1100 + 255) / 256), dim3(256), 0,
                     stream, cf, ff, wPT);
  hipLaunchKernelGGL(selp_kernel, dim3((NC * 10 + 255) / 256), dim3(256), 0,
                     stream, sel, selpT);
  hipLaunchKernelGGL(initT2_kernel, dim3((NBATCH * NBI * NC + 255) / 256),
                     dim3(256), 0, stream, init, initT2);
  hipLaunchKernelGGL(copy_init_kernel,
                     dim3((NBATCH * NC * (NBI / 4) + 255) / 256), dim3(256), 0,
                     stream, (const float4*)init, (float4*)out);
  hipLaunchKernelGGL(sim_kernel, dim3(NBATCH), dim3(NC), 0, stream,
                     bias, applied, convT, (const uint4*)wPT, selpT, initT2, out);
}